// Round 5
// baseline (186.183 us; speedup 1.0000x reference)
//
#include <hip/hip_runtime.h>
#include <hip/hip_bf16.h>
#include <math.h>
#include <float.h>

// Problem constants
#define BSZ 16
#define SEQ 4096
#define HID 768
#define H4  192      // HID/4
#define NM  128      // mentions per batch
#define NSPAN 256    // 2*NM endpoint slots per batch
#define ENT 256
#define NTOT 2048    // BSZ*NM
#define SC  64       // sequence chunk size
#define NCH 64       // SEQ/SC
#define EVR 8        // rows per ev_gemm block
#define LROWS 8      // rows per loss block

// ---------------------------------------------------------------------------
// Kernel A (prep): independent preliminaries fused into one launch.
//   blocks 0..31 : gather label embeddings -> LET[k][j] via LDS transpose
//   blocks 32..127: transpose linear_w [ENT][HID] -> WT [HID][ENT]
//   block 32 t0  : zero the loss completion counter
// ---------------------------------------------------------------------------
__global__ __launch_bounds__(256) void prep_kernel(
    const float* __restrict__ lw, float* __restrict__ WT,
    const float* __restrict__ table, const int* __restrict__ labels,
    float* __restrict__ LET, unsigned int* __restrict__ counter) {
  int bid = blockIdx.x, t = threadIdx.x;
  if (bid < 32) {
    __shared__ float lds[64][ENT + 1];  // +1 pad: column reads conflict-free
    int j0 = bid * 64;
    int g = t >> 6, lane = t & 63;
    for (int rr = 0; rr < 64; rr += 4) {
      int r = rr + g;
      int j = j0 + r;
      int lab = labels[(j >> 7) * 256 + (j & 127)];  // labels[b][0][m]
      float4 v = reinterpret_cast<const float4*>(table + (size_t)lab * ENT)[lane];
      lds[r][lane * 4 + 0] = v.x;
      lds[r][lane * 4 + 1] = v.y;
      lds[r][lane * 4 + 2] = v.z;
      lds[r][lane * 4 + 3] = v.w;
    }
    __syncthreads();
    // wave g writes k = g*64+kk; lane l covers column j0+l -> coalesced 256B
    for (int kk = 0; kk < 64; ++kk) {
      int k = g * 64 + kk;
      LET[(size_t)k * NTOT + j0 + lane] = lds[lane][k];
    }
  } else {
    if (bid == 32 && t == 0) *counter = 0u;
    for (int idx = (bid - 32) * 256 + t; idx < ENT * HID; idx += 96 * 256) {
      int k = idx / ENT, e = idx % ENT;  // WT[k][e] = lw[e][k]
      WT[idx] = lw[e * HID + k];
    }
  }
}

// ---------------------------------------------------------------------------
// Kernel 1: chunked scan over sequence_output.
// Grid: BSZ*NCH blocks, 192 threads (one float4 column of HID each).
// Emits within-chunk cumsum at span endpoints (W) and the chunk total (P).
// NOTE: P stays as raw per-chunk totals — the inter-chunk prefix is folded
// into ev_gemm's staging as an on-the-fly range sum (kills the 12-block
// serial-latency chunk_prefix kernel).
// ---------------------------------------------------------------------------
__global__ __launch_bounds__(192) void span_scan_kernel(
    const float* __restrict__ seq, const int* __restrict__ spans,
    float* __restrict__ W, float* __restrict__ P) {
  int b = blockIdx.x / NCH;
  int c = blockIdx.x % NCH;
  int t = threadIdx.x;  // 0..191

  __shared__ int head[SC + 1];
  __shared__ int nxt[NSPAN];
  __shared__ unsigned int maskw[2];
  __shared__ int has_end;
  for (int i = t; i < SC + 1; i += 192) head[i] = -1;
  if (t < 2) maskw[t] = 0u;
  if (t == 0) has_end = 0;
  __syncthreads();
  for (int j = t; j < NSPAN; j += 192) {
    int e = spans[b * NSPAN + j];  // endpoint in [0, SEQ]
    int ch = e >> 6; if (ch > NCH - 1) ch = NCH - 1;
    if (ch == c) {
      int off = e - c * SC;  // [0, SC]
      nxt[j] = atomicExch(&head[off], j);
      if (off < SC) atomicOr(&maskw[off >> 5], 1u << (off & 31));
      else has_end = 1;
    }
  }
  __syncthreads();
  unsigned long long mask =
      ((unsigned long long)maskw[1] << 32) | maskw[0];
  int emit_end = has_end;

  const float4* seq4 =
      reinterpret_cast<const float4*>(seq) + (size_t)(b * SEQ + c * SC) * H4 + t;
  float4* W4 = reinterpret_cast<float4*>(W);
  float4 acc = make_float4(0.f, 0.f, 0.f, 0.f);
#pragma unroll 8
  for (int s = 0; s < SC; ++s) {
    if (mask & (1ull << s)) {  // wave-uniform, usually false
      for (int p = head[s]; p != -1; p = nxt[p]) {
        W4[(size_t)(b * NSPAN + p) * H4 + t] = acc;
      }
    }
    float4 v = seq4[(size_t)s * H4];
    acc.x += v.x; acc.y += v.y; acc.z += v.z; acc.w += v.w;
  }
  if (emit_end) {
    for (int p = head[SC]; p != -1; p = nxt[p]) {
      W4[(size_t)(b * NSPAN + p) * H4 + t] = acc;
    }
  }
  reinterpret_cast<float4*>(P)[(size_t)(b * NCH + c) * H4 + t] = acc;
}

// ---------------------------------------------------------------------------
// Kernel 2: fused mention-vector construction + entity GEMV.
// Staging computes padded-cumsum differences via on-the-fly chunk range sum:
//   mention_sum = sum_{c0 <= cc < c1} P[b][cc] + w1 - w0
// (independent coalesced float4 loads of L2-resident P — latency-pipelined).
// ---------------------------------------------------------------------------
__global__ __launch_bounds__(256) void ev_gemm_kernel(
    const float* __restrict__ W, const float* __restrict__ P,
    const int* __restrict__ spans, const float* __restrict__ WT,
    const float* __restrict__ bias, float* __restrict__ EVa,
    float* __restrict__ out) {
  int t = threadIdx.x;
  int i0 = blockIdx.x * EVR;
  __shared__ float mv[EVR][HID];

  const float4* W4 = reinterpret_cast<const float4*>(W);
  const float4* P4 = reinterpret_cast<const float4*>(P);
  for (int q = t; q < EVR * H4; q += 256) {
    int r = q / H4, h = q - r * H4;
    int bm = i0 + r;
    int b = bm >> 7, m = bm & (NM - 1);
    int e0 = spans[bm * 2], e1 = spans[bm * 2 + 1];
    int c0 = e0 >> 6; if (c0 > NCH - 1) c0 = NCH - 1;
    int c1 = e1 >> 6; if (c1 > NCH - 1) c1 = NCH - 1;
    // range sum of chunk totals [c0, c1)
    float4 ps = make_float4(0.f, 0.f, 0.f, 0.f);
    size_t pbase = (size_t)b * NCH * H4 + h;
    for (int cc = c0; cc < c1; ++cc) {
      float4 pv = P4[pbase + (size_t)cc * H4];
      ps.x += pv.x; ps.y += pv.y; ps.z += pv.z; ps.w += pv.w;
    }
    float4 w0 = W4[(size_t)(b * NSPAN + 2 * m) * H4 + h];
    float4 w1 = W4[(size_t)(b * NSPAN + 2 * m + 1) * H4 + h];
    int len = e1 - e0;
    float inv = len > 0 ? 1.f / (float)len : 0.f;  // len==0 -> 0 (nan_to_num)
    float4 s4;
    s4.x = (ps.x + w1.x - w0.x) * inv;
    s4.y = (ps.y + w1.y - w0.y) * inv;
    s4.z = (ps.z + w1.z - w0.z) * inv;
    s4.w = (ps.w + w1.w - w0.w) * inv;
    reinterpret_cast<float4*>(&mv[r][0])[h] = s4;
  }
  __syncthreads();

  float acc[EVR];
#pragma unroll
  for (int r = 0; r < EVR; ++r) acc[r] = 0.f;

  for (int k4 = 0; k4 < HID; k4 += 4) {
    float4 mr[EVR];
#pragma unroll
    for (int r = 0; r < EVR; ++r)
      mr[r] = *reinterpret_cast<const float4*>(&mv[r][k4]);  // b128 broadcast
    float wv0 = WT[(size_t)(k4 + 0) * ENT + t];
    float wv1 = WT[(size_t)(k4 + 1) * ENT + t];
    float wv2 = WT[(size_t)(k4 + 2) * ENT + t];
    float wv3 = WT[(size_t)(k4 + 3) * ENT + t];
#pragma unroll
    for (int r = 0; r < EVR; ++r) {
      acc[r] += mr[r].x * wv0 + mr[r].y * wv1 + mr[r].z * wv2 + mr[r].w * wv3;
    }
  }

  float bv = bias[t];
#pragma unroll
  for (int r = 0; r < EVR; ++r) {
    float v = acc[r] + bv;
    EVa[(size_t)(i0 + r) * ENT + t] = v;
    out[1 + (size_t)(i0 + r) * ENT + t] = v;
  }
}

// ---------------------------------------------------------------------------
// Kernel 3: per-row contrastive loss + fused final reduction (last-block
// atomic ticket). All acc indices compile-time constant (rule #20).
// ---------------------------------------------------------------------------
__global__ __launch_bounds__(256) void loss_rows_kernel(
    const float* __restrict__ EVa, const float* __restrict__ LET,
    const int* __restrict__ labels, float* __restrict__ perrow,
    unsigned int* __restrict__ counter, float* __restrict__ out) {
  int t = threadIdx.x;
  int i0 = blockIdx.x * LROWS;
  __shared__ float evs[LROWS][ENT];
  __shared__ float red[LROWS][4];
  __shared__ float diag[LROWS];
  float4* evs4 = reinterpret_cast<float4*>(&evs[0][0]);
  const float4* src = reinterpret_cast<const float4*>(EVa + (size_t)i0 * ENT);
  for (int q = t; q < LROWS * ENT / 4; q += 256) evs4[q] = src[q];
  __syncthreads();

  float acc[LROWS][8];
#pragma unroll
  for (int r = 0; r < LROWS; ++r)
#pragma unroll
    for (int c = 0; c < 8; ++c) acc[r][c] = 0.f;

  for (int k4 = 0; k4 < ENT; k4 += 4) {
    float4 ev[LROWS];
#pragma unroll
    for (int r = 0; r < LROWS; ++r)
      ev[r] = *reinterpret_cast<const float4*>(&evs[r][k4]);  // b128 broadcast
#pragma unroll
    for (int kk = 0; kk < 4; ++kk) {
      float lv[8];
#pragma unroll
      for (int c = 0; c < 8; ++c)
        lv[c] = LET[(size_t)(k4 + kk) * NTOT + c * 256 + t];
#pragma unroll
      for (int c = 0; c < 8; ++c) {
#pragma unroll
        for (int r = 0; r < LROWS; ++r) {
          float e = (kk == 0) ? ev[r].x : (kk == 1) ? ev[r].y
                   : (kk == 2) ? ev[r].z : ev[r].w;
          acc[r][c] += e * lv[c];
        }
      }
    }
  }

  // diagonal logits — compile-time acc indices only
#pragma unroll
  for (int r = 0; r < LROWS; ++r) {
    int i = i0 + r;
    int cdiag = i >> 8;
    int tdiag = i & 255;
#pragma unroll
    for (int c = 0; c < 8; ++c) {
      if (c == cdiag && t == tdiag) diag[r] = acc[r][c];
    }
  }

  int lane = t & 63, wid = t >> 6;
#pragma unroll
  for (int r = 0; r < LROWS; ++r) {
    float m = acc[r][0];
#pragma unroll
    for (int c = 1; c < 8; ++c) m = fmaxf(m, acc[r][c]);
    for (int o = 32; o >= 1; o >>= 1) m = fmaxf(m, __shfl_xor(m, o));
    if (lane == 0) red[r][wid] = m;
  }
  __syncthreads();
  float rowmax[LROWS];
#pragma unroll
  for (int r = 0; r < LROWS; ++r)
    rowmax[r] = fmaxf(fmaxf(red[r][0], red[r][1]), fmaxf(red[r][2], red[r][3]));
  __syncthreads();
#pragma unroll
  for (int r = 0; r < LROWS; ++r) {
    float s = 0.f;
#pragma unroll
    for (int c = 0; c < 8; ++c) s += expf(acc[r][c] - rowmax[r]);
    for (int o = 32; o >= 1; o >>= 1) s += __shfl_xor(s, o);
    if (lane == 0) red[r][wid] = s;
  }
  __syncthreads();
  if (t < LROWS) {
    int r = t;
    float s = red[r][0] + red[r][1] + red[r][2] + red[r][3];
    perrow[i0 + r] = (logf(s) + rowmax[r]) - diag[r];
  }

  // ---- fused finalize: last block to finish reduces perrow -> out[0] ----
  __threadfence();
  __syncthreads();
  __shared__ unsigned int ticket;
  if (t == 0) ticket = atomicAdd(counter, 1u);
  __syncthreads();
  if (ticket == (unsigned)(gridDim.x - 1)) {
    __threadfence();
    float s = 0.f, cnt = 0.f;
    for (int i = t; i < NTOT; i += 256) {
      int status = labels[(i >> 7) * 256 + 128 + (i & 127)];  // labels[b][1][m]
      if (status >= 0) { s += perrow[i]; cnt += 1.f; }
    }
    __shared__ float rs[256], rc[256];
    rs[t] = s; rc[t] = cnt;
    __syncthreads();
    for (int o = 128; o > 0; o >>= 1) {
      if (t < o) { rs[t] += rs[t + o]; rc[t] += rc[t + o]; }
      __syncthreads();
    }
    if (t == 0) {
      float L = rc[0] > 0.f ? rs[0] / rc[0] : 0.f;
      if (isnan(L)) L = 0.f;
      if (isinf(L)) L = L > 0.f ? FLT_MAX : -FLT_MAX;
      out[0] = L;
    }
  }
}

// ---------------------------------------------------------------------------
extern "C" void kernel_launch(void* const* d_in, const int* in_sizes, int n_in,
                              void* d_out, int out_size, void* d_ws,
                              size_t ws_size, hipStream_t stream) {
  const float* seq   = (const float*)d_in[0];  // [16,4096,768]
  const float* lw    = (const float*)d_in[1];  // [256,768]
  const float* lb    = (const float*)d_in[2];  // [256]
  const float* table = (const float*)d_in[3];  // [50000,256]
  const int* spans   = (const int*)d_in[4];    // [16,128,2]
  const int* labels  = (const int*)d_in[5];    // [16,2,128]
  float* out = (float*)d_out;                  // [1 + 16*128*256]
  float* ws = (float*)d_ws;

  // workspace layout (floats)
  float* W      = ws;                              // [16][256][768]
  float* P      = W + (size_t)BSZ * NSPAN * HID;   // [16][64][768]
  float* WT     = P + (size_t)BSZ * NCH * HID;     // [768][256]
  float* EVa    = WT + (size_t)HID * ENT;          // [2048][256]
  float* LET    = EVa + (size_t)NTOT * ENT;        // [256][2048]
  float* perrow = LET + (size_t)ENT * NTOT;        // [2048]
  unsigned int* counter = (unsigned int*)(perrow + NTOT);

  prep_kernel<<<128, 256, 0, stream>>>(lw, WT, table, labels, LET, counter);
  span_scan_kernel<<<BSZ * NCH, 192, 0, stream>>>(seq, spans, W, P);
  ev_gemm_kernel<<<NTOT / EVR, 256, 0, stream>>>(W, P, spans, WT, lb, EVa, out);
  loss_rows_kernel<<<NTOT / LROWS, 256, 0, stream>>>(EVa, LET, labels, perrow,
                                                     counter, out);
}

// Round 6
// 166.352 us; speedup vs baseline: 1.1192x; 1.1192x over previous
//
#include <hip/hip_runtime.h>
#include <hip/hip_bf16.h>
#include <math.h>
#include <float.h>

// Problem constants
#define BSZ 16
#define SEQ 4096
#define HID 768
#define H4  192      // HID/4
#define NM  128      // mentions per batch
#define NSPAN 256    // 2*NM endpoint slots per batch
#define ENT 256
#define NTOT 2048    // BSZ*NM
#define SC  64       // sequence chunk size
#define NCH 64       // SEQ/SC
#define EVR 8        // rows per ev_gemm block
#define LROWS 8      // rows per loss block

// ---------------------------------------------------------------------------
// Kernel A (prep): independent preliminaries fused into one launch.
//   blocks 0..31 : gather label embeddings -> LET[k][j] via LDS transpose
//   blocks 32..127: transpose linear_w [ENT][HID] -> WT [HID][ENT]
//   block 32 t0  : zero the loss completion counter
// ---------------------------------------------------------------------------
__global__ __launch_bounds__(256) void prep_kernel(
    const float* __restrict__ lw, float* __restrict__ WT,
    const float* __restrict__ table, const int* __restrict__ labels,
    float* __restrict__ LET, unsigned int* __restrict__ counter) {
  int bid = blockIdx.x, t = threadIdx.x;
  if (bid < 32) {
    __shared__ float lds[64][ENT + 1];  // +1 pad: column reads conflict-free
    int j0 = bid * 64;
    int g = t >> 6, lane = t & 63;
    for (int rr = 0; rr < 64; rr += 4) {
      int r = rr + g;
      int j = j0 + r;
      int lab = labels[(j >> 7) * 256 + (j & 127)];  // labels[b][0][m]
      float4 v = reinterpret_cast<const float4*>(table + (size_t)lab * ENT)[lane];
      lds[r][lane * 4 + 0] = v.x;
      lds[r][lane * 4 + 1] = v.y;
      lds[r][lane * 4 + 2] = v.z;
      lds[r][lane * 4 + 3] = v.w;
    }
    __syncthreads();
    // wave g writes k = g*64+kk; lane l covers column j0+l -> coalesced 256B
    for (int kk = 0; kk < 64; ++kk) {
      int k = g * 64 + kk;
      LET[(size_t)k * NTOT + j0 + lane] = lds[lane][k];
    }
  } else {
    if (bid == 32 && t == 0) *counter = 0u;
    for (int idx = (bid - 32) * 256 + t; idx < ENT * HID; idx += 96 * 256) {
      int k = idx / ENT, e = idx % ENT;  // WT[k][e] = lw[e][k]
      WT[idx] = lw[e * HID + k];
    }
  }
}

// ---------------------------------------------------------------------------
// Kernel 1: chunked scan over sequence_output (unchanged across rounds).
// ---------------------------------------------------------------------------
__global__ __launch_bounds__(192) void span_scan_kernel(
    const float* __restrict__ seq, const int* __restrict__ spans,
    float* __restrict__ W, float* __restrict__ P) {
  int b = blockIdx.x / NCH;
  int c = blockIdx.x % NCH;
  int t = threadIdx.x;  // 0..191

  __shared__ int head[SC + 1];
  __shared__ int nxt[NSPAN];
  __shared__ unsigned int maskw[2];
  __shared__ int has_end;
  for (int i = t; i < SC + 1; i += 192) head[i] = -1;
  if (t < 2) maskw[t] = 0u;
  if (t == 0) has_end = 0;
  __syncthreads();
  for (int j = t; j < NSPAN; j += 192) {
    int e = spans[b * NSPAN + j];  // endpoint in [0, SEQ]
    int ch = e >> 6; if (ch > NCH - 1) ch = NCH - 1;
    if (ch == c) {
      int off = e - c * SC;  // [0, SC]
      nxt[j] = atomicExch(&head[off], j);
      if (off < SC) atomicOr(&maskw[off >> 5], 1u << (off & 31));
      else has_end = 1;
    }
  }
  __syncthreads();
  unsigned long long mask =
      ((unsigned long long)maskw[1] << 32) | maskw[0];
  int emit_end = has_end;

  const float4* seq4 =
      reinterpret_cast<const float4*>(seq) + (size_t)(b * SEQ + c * SC) * H4 + t;
  float4* W4 = reinterpret_cast<float4*>(W);
  float4 acc = make_float4(0.f, 0.f, 0.f, 0.f);
#pragma unroll 8
  for (int s = 0; s < SC; ++s) {
    if (mask & (1ull << s)) {  // wave-uniform, usually false
      for (int p = head[s]; p != -1; p = nxt[p]) {
        W4[(size_t)(b * NSPAN + p) * H4 + t] = acc;
      }
    }
    float4 v = seq4[(size_t)s * H4];
    acc.x += v.x; acc.y += v.y; acc.z += v.z; acc.w += v.w;
  }
  if (emit_end) {
    for (int p = head[SC]; p != -1; p = nxt[p]) {
      W4[(size_t)(b * NSPAN + p) * H4 + t] = acc;
    }
  }
  reinterpret_cast<float4*>(P)[(size_t)(b * NCH + c) * H4 + t] = acc;
}

// ---------------------------------------------------------------------------
// Kernel 2: exclusive prefix over chunk sums — batched-load version.
// One block per batch b, 192 threads (one float4 column each). Loads 16
// chunk values at once (independent, issued together), then serial adds in
// registers -> latency ~4 batches instead of 64 round-trips.
// ---------------------------------------------------------------------------
__global__ __launch_bounds__(192) void chunk_prefix_kernel(float* __restrict__ P) {
  int b = blockIdx.x;   // 0..15
  int h = threadIdx.x;  // 0..191
  float4* P4 = reinterpret_cast<float4*>(P) + (size_t)b * NCH * H4 + h;
  float4 run = make_float4(0.f, 0.f, 0.f, 0.f);
  for (int cb = 0; cb < NCH; cb += 16) {
    float4 v[16];
#pragma unroll
    for (int i = 0; i < 16; ++i) v[i] = P4[(size_t)(cb + i) * H4];
#pragma unroll
    for (int i = 0; i < 16; ++i) {
      P4[(size_t)(cb + i) * H4] = run;
      run.x += v[i].x; run.y += v[i].y; run.z += v[i].z; run.w += v[i].w;
    }
  }
}

// ---------------------------------------------------------------------------
// Kernel 3: fused mention-vector construction + entity GEMV (R4 staging:
// P holds exclusive prefix; mention sum = (p1+w1) - (p0+w0)).
// ---------------------------------------------------------------------------
__global__ __launch_bounds__(256) void ev_gemm_kernel(
    const float* __restrict__ W, const float* __restrict__ P,
    const int* __restrict__ spans, const float* __restrict__ WT,
    const float* __restrict__ bias, float* __restrict__ EVa,
    float* __restrict__ out) {
  int t = threadIdx.x;
  int i0 = blockIdx.x * EVR;
  __shared__ float mv[EVR][HID];

  const float4* W4 = reinterpret_cast<const float4*>(W);
  const float4* P4 = reinterpret_cast<const float4*>(P);
  for (int q = t; q < EVR * H4; q += 256) {
    int r = q / H4, h = q - r * H4;
    int bm = i0 + r;
    int b = bm >> 7, m = bm & (NM - 1);
    int e0 = spans[bm * 2], e1 = spans[bm * 2 + 1];
    int c0 = e0 >> 6; if (c0 > NCH - 1) c0 = NCH - 1;
    int c1 = e1 >> 6; if (c1 > NCH - 1) c1 = NCH - 1;
    float4 p0 = P4[(size_t)(b * NCH + c0) * H4 + h];
    float4 p1 = P4[(size_t)(b * NCH + c1) * H4 + h];
    float4 w0 = W4[(size_t)(b * NSPAN + 2 * m) * H4 + h];
    float4 w1 = W4[(size_t)(b * NSPAN + 2 * m + 1) * H4 + h];
    int len = e1 - e0;
    float inv = len > 0 ? 1.f / (float)len : 0.f;  // len==0 -> 0 (nan_to_num)
    float4 s4;
    s4.x = ((p1.x + w1.x) - (p0.x + w0.x)) * inv;
    s4.y = ((p1.y + w1.y) - (p0.y + w0.y)) * inv;
    s4.z = ((p1.z + w1.z) - (p0.z + w0.z)) * inv;
    s4.w = ((p1.w + w1.w) - (p0.w + w0.w)) * inv;
    reinterpret_cast<float4*>(&mv[r][0])[h] = s4;
  }
  __syncthreads();

  float acc[EVR];
#pragma unroll
  for (int r = 0; r < EVR; ++r) acc[r] = 0.f;

  for (int k4 = 0; k4 < HID; k4 += 4) {
    float4 mr[EVR];
#pragma unroll
    for (int r = 0; r < EVR; ++r)
      mr[r] = *reinterpret_cast<const float4*>(&mv[r][k4]);  // b128 broadcast
    float wv0 = WT[(size_t)(k4 + 0) * ENT + t];
    float wv1 = WT[(size_t)(k4 + 1) * ENT + t];
    float wv2 = WT[(size_t)(k4 + 2) * ENT + t];
    float wv3 = WT[(size_t)(k4 + 3) * ENT + t];
#pragma unroll
    for (int r = 0; r < EVR; ++r) {
      acc[r] += mr[r].x * wv0 + mr[r].y * wv1 + mr[r].z * wv2 + mr[r].w * wv3;
    }
  }

  float bv = bias[t];
#pragma unroll
  for (int r = 0; r < EVR; ++r) {
    float v = acc[r] + bv;
    EVa[(size_t)(i0 + r) * ENT + t] = v;
    out[1 + (size_t)(i0 + r) * ENT + t] = v;
  }
}

// ---------------------------------------------------------------------------
// Kernel 4: per-row contrastive loss with double-buffered register prefetch
// of LET (hides L2 latency at 1 wave/SIMD occupancy). Plain R2-form FMAs.
// Fused finalize via last-block atomic ticket.
// ---------------------------------------------------------------------------
__global__ __launch_bounds__(256) void loss_rows_kernel(
    const float* __restrict__ EVa, const float* __restrict__ LET,
    const int* __restrict__ labels, float* __restrict__ perrow,
    unsigned int* __restrict__ counter, float* __restrict__ out) {
  int t = threadIdx.x;
  int i0 = blockIdx.x * LROWS;
  __shared__ float evs[LROWS][ENT];
  __shared__ float red[LROWS][4];
  __shared__ float diag[LROWS];
  float4* evs4 = reinterpret_cast<float4*>(&evs[0][0]);
  const float4* src = reinterpret_cast<const float4*>(EVa + (size_t)i0 * ENT);
  for (int q = t; q < LROWS * ENT / 4; q += 256) evs4[q] = src[q];
  __syncthreads();

  float acc[LROWS][8];
#pragma unroll
  for (int r = 0; r < LROWS; ++r)
#pragma unroll
    for (int c = 0; c < 8; ++c) acc[r][c] = 0.f;

  float lvA[4][8], lvB[4][8];
  // prologue: prefetch k = 0..3 into lvA
#pragma unroll
  for (int kk = 0; kk < 4; ++kk)
#pragma unroll
    for (int c = 0; c < 8; ++c)
      lvA[kk][c] = LET[(size_t)kk * NTOT + c * 256 + t];

  for (int k8 = 0; k8 < ENT; k8 += 8) {
    // prefetch k8+4..k8+7 into lvB (issued before consuming lvA)
#pragma unroll
    for (int kk = 0; kk < 4; ++kk)
#pragma unroll
      for (int c = 0; c < 8; ++c)
        lvB[kk][c] = LET[(size_t)((k8 + 4 + kk) & 255) * NTOT + c * 256 + t];
    // FMA k8..k8+3 from lvA
#pragma unroll
    for (int kk = 0; kk < 4; ++kk) {
      float evk[LROWS];
#pragma unroll
      for (int r = 0; r < LROWS; ++r) evk[r] = evs[r][k8 + kk];
#pragma unroll
      for (int c = 0; c < 8; ++c)
#pragma unroll
        for (int r = 0; r < LROWS; ++r) acc[r][c] += evk[r] * lvA[kk][c];
    }
    // prefetch k8+8..k8+11 into lvA (&255 wrap keeps last prefetch in-bounds;
    // its values are never consumed)
#pragma unroll
    for (int kk = 0; kk < 4; ++kk)
#pragma unroll
      for (int c = 0; c < 8; ++c)
        lvA[kk][c] = LET[(size_t)((k8 + 8 + kk) & 255) * NTOT + c * 256 + t];
    // FMA k8+4..k8+7 from lvB
#pragma unroll
    for (int kk = 0; kk < 4; ++kk) {
      float evk[LROWS];
#pragma unroll
      for (int r = 0; r < LROWS; ++r) evk[r] = evs[r][k8 + 4 + kk];
#pragma unroll
      for (int c = 0; c < 8; ++c)
#pragma unroll
        for (int r = 0; r < LROWS; ++r) acc[r][c] += evk[r] * lvB[kk][c];
    }
  }

  // diagonal logits — compile-time acc indices only
#pragma unroll
  for (int r = 0; r < LROWS; ++r) {
    int i = i0 + r;
    int cdiag = i >> 8;
    int tdiag = i & 255;
#pragma unroll
    for (int c = 0; c < 8; ++c) {
      if (c == cdiag && t == tdiag) diag[r] = acc[r][c];
    }
  }

  int lane = t & 63, wid = t >> 6;
#pragma unroll
  for (int r = 0; r < LROWS; ++r) {
    float m = acc[r][0];
#pragma unroll
    for (int c = 1; c < 8; ++c) m = fmaxf(m, acc[r][c]);
    for (int o = 32; o >= 1; o >>= 1) m = fmaxf(m, __shfl_xor(m, o));
    if (lane == 0) red[r][wid] = m;
  }
  __syncthreads();
  float rowmax[LROWS];
#pragma unroll
  for (int r = 0; r < LROWS; ++r)
    rowmax[r] = fmaxf(fmaxf(red[r][0], red[r][1]), fmaxf(red[r][2], red[r][3]));
  __syncthreads();
#pragma unroll
  for (int r = 0; r < LROWS; ++r) {
    float s = 0.f;
#pragma unroll
    for (int c = 0; c < 8; ++c) s += expf(acc[r][c] - rowmax[r]);
    for (int o = 32; o >= 1; o >>= 1) s += __shfl_xor(s, o);
    if (lane == 0) red[r][wid] = s;
  }
  __syncthreads();
  if (t < LROWS) {
    int r = t;
    float s = red[r][0] + red[r][1] + red[r][2] + red[r][3];
    perrow[i0 + r] = (logf(s) + rowmax[r]) - diag[r];
  }

  // ---- fused finalize: last block to finish reduces perrow -> out[0] ----
  __threadfence();
  __syncthreads();
  __shared__ unsigned int ticket;
  if (t == 0) ticket = atomicAdd(counter, 1u);
  __syncthreads();
  if (ticket == (unsigned)(gridDim.x - 1)) {
    __threadfence();
    float s = 0.f, cnt = 0.f;
    for (int i = t; i < NTOT; i += 256) {
      int status = labels[(i >> 7) * 256 + 128 + (i & 127)];  // labels[b][1][m]
      if (status >= 0) { s += perrow[i]; cnt += 1.f; }
    }
    __shared__ float rs[256], rc[256];
    rs[t] = s; rc[t] = cnt;
    __syncthreads();
    for (int o = 128; o > 0; o >>= 1) {
      if (t < o) { rs[t] += rs[t + o]; rc[t] += rc[t + o]; }
      __syncthreads();
    }
    if (t == 0) {
      float L = rc[0] > 0.f ? rs[0] / rc[0] : 0.f;
      if (isnan(L)) L = 0.f;
      if (isinf(L)) L = L > 0.f ? FLT_MAX : -FLT_MAX;
      out[0] = L;
    }
  }
}

// ---------------------------------------------------------------------------
extern "C" void kernel_launch(void* const* d_in, const int* in_sizes, int n_in,
                              void* d_out, int out_size, void* d_ws,
                              size_t ws_size, hipStream_t stream) {
  const float* seq   = (const float*)d_in[0];  // [16,4096,768]
  const float* lw    = (const float*)d_in[1];  // [256,768]
  const float* lb    = (const float*)d_in[2];  // [256]
  const float* table = (const float*)d_in[3];  // [50000,256]
  const int* spans   = (const int*)d_in[4];    // [16,128,2]
  const int* labels  = (const int*)d_in[5];    // [16,2,128]
  float* out = (float*)d_out;                  // [1 + 16*128*256]
  float* ws = (float*)d_ws;

  // workspace layout (floats)
  float* W      = ws;                              // [16][256][768]
  float* P      = W + (size_t)BSZ * NSPAN * HID;   // [16][64][768]
  float* WT     = P + (size_t)BSZ * NCH * HID;     // [768][256]
  float* EVa    = WT + (size_t)HID * ENT;          // [2048][256]
  float* LET    = EVa + (size_t)NTOT * ENT;        // [256][2048]
  float* perrow = LET + (size_t)ENT * NTOT;        // [2048]
  unsigned int* counter = (unsigned int*)(perrow + NTOT);

  prep_kernel<<<128, 256, 0, stream>>>(lw, WT, table, labels, LET, counter);
  span_scan_kernel<<<BSZ * NCH, 192, 0, stream>>>(seq, spans, W, P);
  chunk_prefix_kernel<<<BSZ, 192, 0, stream>>>(P);
  ev_gemm_kernel<<<NTOT / EVR, 256, 0, stream>>>(W, P, spans, WT, lb, EVa, out);
  loss_rows_kernel<<<NTOT / LROWS, 256, 0, stream>>>(EVa, LET, labels, perrow,
                                                     counter, out);
}